// Round 4
// baseline (157.822 us; speedup 1.0000x reference)
//
#include <hip/hip_runtime.h>

#define V3 (128 * 128 * 128)   // 2097152 voxels per volume

// ---------------- block reduction (wave64) ----------------
__device__ __forceinline__ float block_reduce(float v, float* sm) {
#pragma unroll
  for (int off = 32; off > 0; off >>= 1) v += __shfl_down(v, off, 64);
  int lane = threadIdx.x & 63;
  int wid  = threadIdx.x >> 6;
  if (lane == 0) sm[wid] = v;
  __syncthreads();
  float r = 0.f;
  if ((int)threadIdx.x < (int)(blockDim.x >> 6)) r = sm[threadIdx.x];
  if (wid == 0) {
#pragma unroll
    for (int off = 4; off > 0; off >>= 1) r += __shfl_down(r, off, 64);
  }
  __syncthreads();
  return r;  // valid on thread 0
}

__device__ __forceinline__ float4 ldz(const float* __restrict__ p, size_t off,
                                      bool v) {
  const float4 q = *(const float4*)(p + off);
  float4 r;
  r.x = v ? q.x : 0.f; r.y = v ? q.y : 0.f;
  r.z = v ? q.z : 0.f; r.w = v ? q.w : 0.f;
  return r;
}

// ---------------- pred_mask area sums (per t), float4 ----------------
__global__ __launch_bounds__(256) void area_kernel(const float* __restrict__ pm,
                                                   float* __restrict__ acc) {
  __shared__ float sm[8];
  const int t = blockIdx.y;
  const float* p = pm + (size_t)t * V3;
  const int n4 = V3 / 4;
  float s = 0.f;
  for (int i = blockIdx.x * blockDim.x + threadIdx.x; i < n4;
       i += gridDim.x * blockDim.x) {
    float4 a = *(const float4*)(p + 4 * (size_t)i);
    s += (a.x + a.y) + (a.z + a.w);
  }
  s = block_reduce(s, sm);
  if (threadIdx.x == 0) atomicAdd(acc + t, s);
}

// ---------------- flow gradient: register d-walk, 2 loads/iter ----------------
// grid (16 h-tiles, 8 d-tiles, 9 c), block 256 = 8 h-rows x 32 w4.
__global__ __launch_bounds__(256) void grad_kernel(const float* __restrict__ fl,
                                                   float* __restrict__ acc) {
  __shared__ float sm[8];
  const int w4 = threadIdx.x & 31;
  const int hl = threadIdx.x >> 5;           // 0..7
  const int h  = blockIdx.x * 8 + hl;        // 0..127
  const int d0 = blockIdx.y * 16;
  const int c  = blockIdx.z;                 // 0..8
  const float* p = fl + (size_t)c * V3 + (size_t)h * 128 + w4 * 4;
  const bool hv = (h < 127);

  float s = 0.f;
  float4 cur  = *(const float4*)(p + (size_t)d0 * 16384);
  float4 curh = hv ? *(const float4*)(p + (size_t)d0 * 16384 + 128) : cur;

#pragma unroll
  for (int dd = 0; dd < 16; ++dd) {
    const int d = d0 + dd;
    const bool dv = (d < 127);
    float4 nxt = cur, nxth = curh;
    if (dv) {
      nxt = *(const float4*)(p + (size_t)(d + 1) * 16384);
      if (hv) nxth = *(const float4*)(p + (size_t)(d + 1) * 16384 + 128);
    }
    float x;
    x = cur.y - cur.x; s += x * x;
    x = cur.z - cur.y; s += x * x;
    x = cur.w - cur.z; s += x * x;
    float nx = __shfl_down(cur.x, 1, 64);
    if (w4 != 31) { x = nx - cur.w; s += x * x; }
    if (hv) {
      x = curh.x - cur.x; s += x * x;
      x = curh.y - cur.y; s += x * x;
      x = curh.z - cur.z; s += x * x;
      x = curh.w - cur.w; s += x * x;
    }
    if (dv) {
      x = nxt.x - cur.x; s += x * x;
      x = nxt.y - cur.y; s += x * x;
      x = nxt.z - cur.z; s += x * x;
      x = nxt.w - cur.w; s += x * x;
    }
    cur = nxt; curh = nxth;
  }
  s = block_reduce(s, sm);
  if (threadIdx.x == 0) atomicAdd(acc, s);
}

// ---------------- NCC pass 1: W-window + H-window box sums ----------------
// Block = 256 = 2 d-slices x 128 w. Grid = (16 h-chunks of 8, 64 d-pairs, NT).
// Single sync/row: stage row hh+1 into alternate buffer while computing hh.
template <bool WITH_I>
__global__ __launch_bounds__(256) void n1_kernel(const float* __restrict__ I0,
                                                 const float* __restrict__ Jall,
                                                 float* __restrict__ FI,
                                                 float* __restrict__ FJall) {
  constexpr int NF = WITH_I ? 5 : 3;
  __shared__ float sI[2][2][136];
  __shared__ float sJ[2][2][136];
  __shared__ float ring[2][9][NF][128];

  const int tz = blockIdx.z;
  const float* J = Jall + (size_t)tz * V3;
  float* FJ = FJall + (size_t)tz * 3 * (size_t)V3;

  const int w  = threadIdx.x & 127;
  const int dl = threadIdx.x >> 7;
  const int d  = blockIdx.y * 2 + dl;
  const int h0 = blockIdx.x * 8;
  const float* Ib = I0 + (size_t)d * 16384;
  const float* Jb = J  + (size_t)d * 16384;

  // constant halo zeros (both buffers), written once
  if (w < 4) {
    sI[dl][0][w] = 0.f; sI[dl][1][w] = 0.f;
    sJ[dl][0][w] = 0.f; sJ[dl][1][w] = 0.f;
  }
  if (w >= 124) {
    sI[dl][0][w + 8] = 0.f; sI[dl][1][w + 8] = 0.f;
    sJ[dl][0][w + 8] = 0.f; sJ[dl][1][w + 8] = 0.f;
  }
  // thread-private ring columns: no sync needed ever
#pragma unroll
  for (int sl = 0; sl < 9; ++sl)
#pragma unroll
    for (int f = 0; f < NF; ++f) ring[dl][sl][f][w] = 0.f;

  auto stage = [&](int hh) {
    if (hh >= 0 && hh < 128) {
      const int b = hh & 1;
      if (w < 32) {
        float4 v = *(const float4*)(Ib + hh * 128 + w * 4);
        *(float4*)&sI[dl][b][4 + w * 4] = v;
      } else if (w < 64) {
        const int l = w - 32;
        float4 v = *(const float4*)(Jb + hh * 128 + l * 4);
        *(float4*)&sJ[dl][b][4 + l * 4] = v;
      }
    }
  };

  float S[NF];
#pragma unroll
  for (int f = 0; f < NF; ++f) S[f] = 0.f;

  stage(h0 - 4);
  int slot = (h0 + 32) % 9;  // slot for hh = h0-4

  for (int hh = h0 - 4; hh < h0 + 12; ++hh) {
    __syncthreads();      // staged row for this iter visible; prev reads done
    stage(hh + 1);        // writes alternate buffer
    const int b = hh & 1;
    const bool valid = (hh >= 0) && (hh < 128);

    float Wn[NF];
#pragma unroll
    for (int f = 0; f < NF; ++f) Wn[f] = 0.f;
    if (valid) {
#pragma unroll
      for (int k = 0; k < 9; ++k) {
        float a = sI[dl][b][w + k];
        float bb = sJ[dl][b][w + k];
        if (WITH_I) {
          Wn[0] += a; Wn[1] += a * a;
          Wn[2] += bb; Wn[3] += bb * bb; Wn[4] += a * bb;
        } else {
          Wn[0] += bb; Wn[1] += bb * bb; Wn[2] += a * bb;
        }
      }
    }

#pragma unroll
    for (int f = 0; f < NF; ++f) {
      float old = ring[dl][slot][f][w];
      ring[dl][slot][f][w] = Wn[f];
      S[f] += Wn[f] - old;
    }
    ++slot; if (slot == 9) slot = 0;

    const int ho = hh - 4;
    if (ho >= h0) {
      size_t base = (size_t)d * 16384 + (size_t)ho * 128 + w;
      if (WITH_I) {
        FI[base]                  = S[0];
        FI[(size_t)V3 + base]     = S[1];
        FJ[base]                  = S[2];
        FJ[(size_t)V3 + base]     = S[3];
        FJ[2 * (size_t)V3 + base] = S[4];
      } else {
        FJ[base]                  = S[0];
        FJ[(size_t)V3 + base]     = S[1];
        FJ[2 * (size_t)V3 + base] = S[2];
      }
    }
  }
}

// ---------------- NCC pass 2: float4 running D-window + cc + reduce ----------
// Block = 256 = 8 h-rows x 32 w4. Grid = (16 h-tiles, 16 d-chunks of 8, NT).
__global__ __launch_bounds__(256) void n2_kernel(const float* __restrict__ FI,
                                                 const float* __restrict__ FJall,
                                                 float* __restrict__ acc) {
  __shared__ float sm[8];
  const float* FJ = FJall + (size_t)blockIdx.z * 3 * (size_t)V3;
  const int w4 = threadIdx.x & 31;
  const int h  = blockIdx.x * 8 + (threadIdx.x >> 5);
  const int d0 = blockIdx.y * 8;
  const size_t hw = (size_t)h * 128 + w4 * 4;

  const float* P0 = FI;
  const float* P1 = FI + (size_t)V3;
  const float* P2 = FJ;
  const float* P3 = FJ + (size_t)V3;
  const float* P4 = FJ + 2 * (size_t)V3;

  float4 S0 = {0,0,0,0}, S1 = {0,0,0,0}, S2 = {0,0,0,0},
         S3 = {0,0,0,0}, S4 = {0,0,0,0};
#pragma unroll
  for (int k = 0; k < 9; ++k) {
    int dd = d0 - 4 + k;
    bool v = (dd >= 0) && (dd < 128);
    size_t a = (size_t)(v ? dd : 0) * 16384 + hw;
    float4 q;
    q = ldz(P0, a, v); S0.x += q.x; S0.y += q.y; S0.z += q.z; S0.w += q.w;
    q = ldz(P1, a, v); S1.x += q.x; S1.y += q.y; S1.z += q.z; S1.w += q.w;
    q = ldz(P2, a, v); S2.x += q.x; S2.y += q.y; S2.z += q.z; S2.w += q.w;
    q = ldz(P3, a, v); S3.x += q.x; S3.y += q.y; S3.z += q.z; S3.w += q.w;
    q = ldz(P4, a, v); S4.x += q.x; S4.y += q.y; S4.z += q.z; S4.w += q.w;
  }

  const float inv_win = 1.0f / 729.0f;
  float accv = 0.f;
#pragma unroll
  for (int dd = 0; dd < 8; ++dd) {
    const int d = d0 + dd;
    {
      float c0, iv, jv;
      c0 = S4.x - S0.x * S2.x * inv_win;
      iv = S1.x - S0.x * S0.x * inv_win;
      jv = S3.x - S2.x * S2.x * inv_win;
      accv += c0 * c0 * __builtin_amdgcn_rcpf(iv * jv + 1e-5f);
      c0 = S4.y - S0.y * S2.y * inv_win;
      iv = S1.y - S0.y * S0.y * inv_win;
      jv = S3.y - S2.y * S2.y * inv_win;
      accv += c0 * c0 * __builtin_amdgcn_rcpf(iv * jv + 1e-5f);
      c0 = S4.z - S0.z * S2.z * inv_win;
      iv = S1.z - S0.z * S0.z * inv_win;
      jv = S3.z - S2.z * S2.z * inv_win;
      accv += c0 * c0 * __builtin_amdgcn_rcpf(iv * jv + 1e-5f);
      c0 = S4.w - S0.w * S2.w * inv_win;
      iv = S1.w - S0.w * S0.w * inv_win;
      jv = S3.w - S2.w * S2.w * inv_win;
      accv += c0 * c0 * __builtin_amdgcn_rcpf(iv * jv + 1e-5f);
    }
    const int da = d + 5, ds = d - 4;
    const bool va = da < 128, vs = ds >= 0;
    const size_t aa = (size_t)(va ? da : 0) * 16384 + hw;
    const size_t as = (size_t)(vs ? ds : 0) * 16384 + hw;
    float4 q, r;
    q = ldz(P0, aa, va); r = ldz(P0, as, vs);
    S0.x += q.x - r.x; S0.y += q.y - r.y; S0.z += q.z - r.z; S0.w += q.w - r.w;
    q = ldz(P1, aa, va); r = ldz(P1, as, vs);
    S1.x += q.x - r.x; S1.y += q.y - r.y; S1.z += q.z - r.z; S1.w += q.w - r.w;
    q = ldz(P2, aa, va); r = ldz(P2, as, vs);
    S2.x += q.x - r.x; S2.y += q.y - r.y; S2.z += q.z - r.z; S2.w += q.w - r.w;
    q = ldz(P3, aa, va); r = ldz(P3, as, vs);
    S3.x += q.x - r.x; S3.y += q.y - r.y; S3.z += q.z - r.z; S3.w += q.w - r.w;
    q = ldz(P4, aa, va); r = ldz(P4, as, vs);
    S4.x += q.x - r.x; S4.y += q.y - r.y; S4.z += q.z - r.z; S4.w += q.w - r.w;
  }

  accv = block_reduce(accv, sm);
  if (threadIdx.x == 0) atomicAdd(acc, accv);
}

// ---------------- final scalar combine ----------------
__global__ void final_kernel(const float* __restrict__ ws,
                             const float* __restrict__ td,
                             float* __restrict__ out) {
  if (threadIdx.x != 0 || blockIdx.x != 0) return;
  float area[4];
  float amax = -1e30f;
#pragma unroll
  for (int t = 0; t < 4; ++t) {
    area[t] = ws[t];
    amax = fmaxf(amax, area[t]);
  }
  float a[4];
#pragma unroll
  for (int t = 0; t < 4; ++t) a[t] = area[t] / amax;

  float sc = 0.f;
  int cnt = 0;
  for (int i = 0; i < 2; ++i)
    for (int j = i + 1; j < 3; ++j)
      for (int k = j + 1; k < 4; ++k) {
        float lam = (td[j] - td[i] + 1e-5f) / (td[k] - td[i] + 1e-5f);
        float e = a[j] - a[i] - lam * (a[k] - a[i]);
        sc += e * e;
        ++cnt;
      }
  sc /= (float)cnt;

  float ncc  = 1.0f - ws[7] / (3.0f * (float)V3);
  float grad = ws[4] / (3.0f * 9.0f * 127.0f * 128.0f * 128.0f);
  out[0] = ncc + 0.1f * grad + 0.1f * sc;
}

extern "C" void kernel_launch(void* const* d_in, const int* in_sizes, int n_in,
                              void* d_out, int out_size, void* d_ws, size_t ws_size,
                              hipStream_t stream) {
  const float* image      = (const float*)d_in[0];
  // d_in[1] = mask (unused by the reference loss)
  const float* pred_image = (const float*)d_in[2];
  const float* pred_mask  = (const float*)d_in[3];
  const float* flow       = (const float*)d_in[4];
  const float* time_diff  = (const float*)d_in[5];
  float* out = (float*)d_out;
  float* wsf = (float*)d_ws;
  float* FI  = wsf + 64;                 // 2 planes (I_sum, I2_sum)
  float* FJ  = FI + 2 * (size_t)V3;      // J plane-triples

  // zero scalar accumulators: [0..3] area, [4] grad sum, [7] cc sum
  hipMemsetAsync(d_ws, 0, 256, stream);

  hipLaunchKernelGGL(area_kernel, dim3(512, 4), dim3(256), 0, stream,
                     pred_mask, wsf);
  hipLaunchKernelGGL(grad_kernel, dim3(16, 8, 9), dim3(256), 0, stream,
                     flow, wsf + 4);

  const size_t need_fused = (64 + 11 * (size_t)V3) * sizeof(float);
  if (ws_size >= need_fused) {
    // fused path: FJ holds 3 t-triples (9 planes) concurrently
    hipLaunchKernelGGL((n1_kernel<true>), dim3(16, 64, 1), dim3(256), 0, stream,
                       image, pred_image + (size_t)V3, FI, FJ);
    hipLaunchKernelGGL((n1_kernel<false>), dim3(16, 64, 2), dim3(256), 0, stream,
                       image, pred_image + 2 * (size_t)V3, FI,
                       FJ + 3 * (size_t)V3);
    hipLaunchKernelGGL(n2_kernel, dim3(16, 16, 3), dim3(256), 0, stream,
                       FI, FJ, wsf + 7);
  } else {
    // sequential path: one J triple reused across t (5 planes total)
    for (int t = 0; t < 3; ++t) {
      const float* J = pred_image + (size_t)(t + 1) * V3;
      if (t == 0) {
        hipLaunchKernelGGL((n1_kernel<true>), dim3(16, 64, 1), dim3(256), 0,
                           stream, image, J, FI, FJ);
      } else {
        hipLaunchKernelGGL((n1_kernel<false>), dim3(16, 64, 1), dim3(256), 0,
                           stream, image, J, FI, FJ);
      }
      hipLaunchKernelGGL(n2_kernel, dim3(16, 16, 1), dim3(256), 0, stream,
                         FI, FJ, wsf + 7);
    }
  }

  hipLaunchKernelGGL(final_kernel, dim3(1), dim3(1), 0, stream,
                     wsf, time_diff, out);
}

// Round 5
// 153.870 us; speedup vs baseline: 1.0257x; 1.0257x over previous
//
#include <hip/hip_runtime.h>

#define V3 (128 * 128 * 128)   // 2097152 voxels per volume

// ---------------- block reduction (wave64) ----------------
__device__ __forceinline__ float block_reduce(float v, float* sm) {
#pragma unroll
  for (int off = 32; off > 0; off >>= 1) v += __shfl_down(v, off, 64);
  int lane = threadIdx.x & 63;
  int wid  = threadIdx.x >> 6;
  if (lane == 0) sm[wid] = v;
  __syncthreads();
  float r = 0.f;
  if ((int)threadIdx.x < (int)(blockDim.x >> 6)) r = sm[threadIdx.x];
  if (wid == 0) {
#pragma unroll
    for (int off = 4; off > 0; off >>= 1) r += __shfl_down(r, off, 64);
  }
  __syncthreads();
  return r;  // valid on thread 0
}

__device__ __forceinline__ float4 ldz(const float* __restrict__ p, size_t off,
                                      bool v) {
  const float4 q = *(const float4*)(p + off);
  float4 r;
  r.x = v ? q.x : 0.f; r.y = v ? q.y : 0.f;
  r.z = v ? q.z : 0.f; r.w = v ? q.w : 0.f;
  return r;
}

__device__ __forceinline__ void add4(float4& a, const float4 b) {
  a.x += b.x; a.y += b.y; a.z += b.z; a.w += b.w;
}

__device__ __forceinline__ float ccf(float i, float i2, float j, float j2,
                                     float ij) {
  const float inv_win = 1.0f / 729.0f;
  float cross = ij - i * j * inv_win;
  float iv    = i2 - i * i * inv_win;
  float jv    = j2 - j * j * inv_win;
  return cross * cross * __builtin_amdgcn_rcpf(iv * jv + 1e-5f);
}

// ---------------- pred_mask area sums (per t), float4 ----------------
__global__ __launch_bounds__(256) void area_kernel(const float* __restrict__ pm,
                                                   float* __restrict__ acc) {
  __shared__ float sm[8];
  const int t = blockIdx.y;
  const float* p = pm + (size_t)t * V3;
  const int n4 = V3 / 4;
  float s = 0.f;
  for (int i = blockIdx.x * blockDim.x + threadIdx.x; i < n4;
       i += gridDim.x * blockDim.x) {
    float4 a = *(const float4*)(p + 4 * (size_t)i);
    s += (a.x + a.y) + (a.z + a.w);
  }
  s = block_reduce(s, sm);
  if (threadIdx.x == 0) atomicAdd(acc + t, s);
}

// ---------------- flow gradient: register d-walk, 2 loads/iter ----------------
// grid (16 h-tiles, 8 d-tiles, 9 c), block 256 = 8 h-rows x 32 w4.
__global__ __launch_bounds__(256) void grad_kernel(const float* __restrict__ fl,
                                                   float* __restrict__ acc) {
  __shared__ float sm[8];
  const int w4 = threadIdx.x & 31;
  const int hl = threadIdx.x >> 5;           // 0..7
  const int h  = blockIdx.x * 8 + hl;        // 0..127
  const int d0 = blockIdx.y * 16;
  const int c  = blockIdx.z;                 // 0..8
  const float* p = fl + (size_t)c * V3 + (size_t)h * 128 + w4 * 4;
  const bool hv = (h < 127);

  float s = 0.f;
  float4 cur  = *(const float4*)(p + (size_t)d0 * 16384);
  float4 curh = hv ? *(const float4*)(p + (size_t)d0 * 16384 + 128) : cur;

#pragma unroll
  for (int dd = 0; dd < 16; ++dd) {
    const int d = d0 + dd;
    const bool dv = (d < 127);
    float4 nxt = cur, nxth = curh;
    if (dv) {
      nxt = *(const float4*)(p + (size_t)(d + 1) * 16384);
      if (hv) nxth = *(const float4*)(p + (size_t)(d + 1) * 16384 + 128);
    }
    float x;
    x = cur.y - cur.x; s += x * x;
    x = cur.z - cur.y; s += x * x;
    x = cur.w - cur.z; s += x * x;
    float nx = __shfl_down(cur.x, 1, 64);
    if (w4 != 31) { x = nx - cur.w; s += x * x; }
    if (hv) {
      x = curh.x - cur.x; s += x * x;
      x = curh.y - cur.y; s += x * x;
      x = curh.z - cur.z; s += x * x;
      x = curh.w - cur.w; s += x * x;
    }
    if (dv) {
      x = nxt.x - cur.x; s += x * x;
      x = nxt.y - cur.y; s += x * x;
      x = nxt.z - cur.z; s += x * x;
      x = nxt.w - cur.w; s += x * x;
    }
    cur = nxt; curh = nxth;
  }
  s = block_reduce(s, sm);
  if (threadIdx.x == 0) atomicAdd(acc, s);
}

// ---------------- NCC pass 1: W-window + H-window box sums ----------------
// Block = 256 = 2 d-slices x 128 w. Grid = (8 h-chunks of 16, 64 d-pairs, NT).
// Single sync/row: stage row hh+1 into alternate buffer while computing hh.
template <bool WITH_I>
__global__ __launch_bounds__(256) void n1_kernel(const float* __restrict__ I0,
                                                 const float* __restrict__ Jall,
                                                 float* __restrict__ FI,
                                                 float* __restrict__ FJall) {
  constexpr int NF = WITH_I ? 5 : 3;
  __shared__ float sI[2][2][136];
  __shared__ float sJ[2][2][136];
  __shared__ float ring[2][9][NF][128];

  const int tz = blockIdx.z;
  const float* J = Jall + (size_t)tz * V3;
  float* FJ = FJall + (size_t)tz * 3 * (size_t)V3;

  const int w  = threadIdx.x & 127;
  const int dl = threadIdx.x >> 7;
  const int d  = blockIdx.y * 2 + dl;
  const int h0 = blockIdx.x * 16;
  const float* Ib = I0 + (size_t)d * 16384;
  const float* Jb = J  + (size_t)d * 16384;

  // constant halo zeros (both buffers), written once
  if (w < 4) {
    sI[dl][0][w] = 0.f; sI[dl][1][w] = 0.f;
    sJ[dl][0][w] = 0.f; sJ[dl][1][w] = 0.f;
  }
  if (w >= 124) {
    sI[dl][0][w + 8] = 0.f; sI[dl][1][w + 8] = 0.f;
    sJ[dl][0][w + 8] = 0.f; sJ[dl][1][w + 8] = 0.f;
  }
  // thread-private ring columns: no sync needed ever
#pragma unroll
  for (int sl = 0; sl < 9; ++sl)
#pragma unroll
    for (int f = 0; f < NF; ++f) ring[dl][sl][f][w] = 0.f;

  auto stage = [&](int hh) {
    if (hh >= 0 && hh < 128) {
      const int b = hh & 1;
      if (w < 32) {
        float4 v = *(const float4*)(Ib + hh * 128 + w * 4);
        *(float4*)&sI[dl][b][4 + w * 4] = v;
      } else if (w < 64) {
        const int l = w - 32;
        float4 v = *(const float4*)(Jb + hh * 128 + l * 4);
        *(float4*)&sJ[dl][b][4 + l * 4] = v;
      }
    }
  };

  float S[NF];
#pragma unroll
  for (int f = 0; f < NF; ++f) S[f] = 0.f;

  stage(h0 - 4);
  int slot = (h0 + 32) % 9;  // slot for hh = h0-4

  for (int hh = h0 - 4; hh < h0 + 20; ++hh) {
    __syncthreads();      // staged row for this iter visible; prev reads done
    stage(hh + 1);        // writes alternate buffer
    const int b = hh & 1;
    const bool valid = (hh >= 0) && (hh < 128);

    float Wn[NF];
#pragma unroll
    for (int f = 0; f < NF; ++f) Wn[f] = 0.f;
    if (valid) {
#pragma unroll
      for (int k = 0; k < 9; ++k) {
        float a = sI[dl][b][w + k];
        float bb = sJ[dl][b][w + k];
        if (WITH_I) {
          Wn[0] += a; Wn[1] += a * a;
          Wn[2] += bb; Wn[3] += bb * bb; Wn[4] += a * bb;
        } else {
          Wn[0] += bb; Wn[1] += bb * bb; Wn[2] += a * bb;
        }
      }
    }

#pragma unroll
    for (int f = 0; f < NF; ++f) {
      float old = ring[dl][slot][f][w];
      ring[dl][slot][f][w] = Wn[f];
      S[f] += Wn[f] - old;
    }
    ++slot; if (slot == 9) slot = 0;

    const int ho = hh - 4;
    if (ho >= h0) {
      size_t base = (size_t)d * 16384 + (size_t)ho * 128 + w;
      if (WITH_I) {
        FI[base]                  = S[0];
        FI[(size_t)V3 + base]     = S[1];
        FJ[base]                  = S[2];
        FJ[(size_t)V3 + base]     = S[3];
        FJ[2 * (size_t)V3 + base] = S[4];
      } else {
        FJ[base]                  = S[0];
        FJ[(size_t)V3 + base]     = S[1];
        FJ[2 * (size_t)V3 + base] = S[2];
      }
    }
  }
}

// ---------------- NCC pass 2: direct 12-slice accumulate, no dep chains ------
// Block = 256 = 8 h-rows x 32 w4. Grid = (16 h-tiles, 32 d-chunks of 4, NT).
// Thread owns 4 d-outputs; loads 12 covering slices x 5 fields (60 independent
// float4 loads), accumulates each slice into the windows it covers.
__global__ __launch_bounds__(256, 2) void n2_kernel(const float* __restrict__ FI,
                                                    const float* __restrict__ FJall,
                                                    float* __restrict__ acc) {
  __shared__ float sm[8];
  const float* FJ = FJall + (size_t)blockIdx.z * 3 * (size_t)V3;
  const int w4 = threadIdx.x & 31;
  const int h  = blockIdx.x * 8 + (threadIdx.x >> 5);
  const int d0 = blockIdx.y * 4;
  const size_t hw = (size_t)h * 128 + w4 * 4;

  const float* P0 = FI;
  const float* P1 = FI + (size_t)V3;
  const float* P2 = FJ;
  const float* P3 = FJ + (size_t)V3;
  const float* P4 = FJ + 2 * (size_t)V3;

  float4 S[4][5];
#pragma unroll
  for (int o = 0; o < 4; ++o)
#pragma unroll
    for (int f = 0; f < 5; ++f) S[o][f] = make_float4(0.f, 0.f, 0.f, 0.f);

#pragma unroll
  for (int k = 0; k < 12; ++k) {
    const int sidx = d0 - 4 + k;
    const bool v = (sidx >= 0) && (sidx < 128);
    const size_t a = (size_t)(v ? sidx : 0) * 16384 + hw;
    float4 q0 = ldz(P0, a, v);
    float4 q1 = ldz(P1, a, v);
    float4 q2 = ldz(P2, a, v);
    float4 q3 = ldz(P3, a, v);
    float4 q4 = ldz(P4, a, v);
#pragma unroll
    for (int o = 0; o < 4; ++o) {
      if (o <= k && k <= o + 8) {   // compile-time per (k,o)
        add4(S[o][0], q0);
        add4(S[o][1], q1);
        add4(S[o][2], q2);
        add4(S[o][3], q3);
        add4(S[o][4], q4);
      }
    }
  }

  float accv = 0.f;
#pragma unroll
  for (int o = 0; o < 4; ++o) {
    accv += ccf(S[o][0].x, S[o][1].x, S[o][2].x, S[o][3].x, S[o][4].x);
    accv += ccf(S[o][0].y, S[o][1].y, S[o][2].y, S[o][3].y, S[o][4].y);
    accv += ccf(S[o][0].z, S[o][1].z, S[o][2].z, S[o][3].z, S[o][4].z);
    accv += ccf(S[o][0].w, S[o][1].w, S[o][2].w, S[o][3].w, S[o][4].w);
  }

  accv = block_reduce(accv, sm);
  if (threadIdx.x == 0) atomicAdd(acc, accv);
}

// ---------------- final scalar combine ----------------
__global__ void final_kernel(const float* __restrict__ ws,
                             const float* __restrict__ td,
                             float* __restrict__ out) {
  if (threadIdx.x != 0 || blockIdx.x != 0) return;
  float area[4];
  float amax = -1e30f;
#pragma unroll
  for (int t = 0; t < 4; ++t) {
    area[t] = ws[t];
    amax = fmaxf(amax, area[t]);
  }
  float a[4];
#pragma unroll
  for (int t = 0; t < 4; ++t) a[t] = area[t] / amax;

  float sc = 0.f;
  int cnt = 0;
  for (int i = 0; i < 2; ++i)
    for (int j = i + 1; j < 3; ++j)
      for (int k = j + 1; k < 4; ++k) {
        float lam = (td[j] - td[i] + 1e-5f) / (td[k] - td[i] + 1e-5f);
        float e = a[j] - a[i] - lam * (a[k] - a[i]);
        sc += e * e;
        ++cnt;
      }
  sc /= (float)cnt;

  float ncc  = 1.0f - ws[7] / (3.0f * (float)V3);
  float grad = ws[4] / (3.0f * 9.0f * 127.0f * 128.0f * 128.0f);
  out[0] = ncc + 0.1f * grad + 0.1f * sc;
}

extern "C" void kernel_launch(void* const* d_in, const int* in_sizes, int n_in,
                              void* d_out, int out_size, void* d_ws, size_t ws_size,
                              hipStream_t stream) {
  const float* image      = (const float*)d_in[0];
  // d_in[1] = mask (unused by the reference loss)
  const float* pred_image = (const float*)d_in[2];
  const float* pred_mask  = (const float*)d_in[3];
  const float* flow       = (const float*)d_in[4];
  const float* time_diff  = (const float*)d_in[5];
  float* out = (float*)d_out;
  float* wsf = (float*)d_ws;
  float* FI  = wsf + 64;                 // 2 planes (I_sum, I2_sum)
  float* FJ  = FI + 2 * (size_t)V3;      // J plane-triples

  // zero scalar accumulators: [0..3] area, [4] grad sum, [7] cc sum
  hipMemsetAsync(d_ws, 0, 256, stream);

  hipLaunchKernelGGL(area_kernel, dim3(512, 4), dim3(256), 0, stream,
                     pred_mask, wsf);
  hipLaunchKernelGGL(grad_kernel, dim3(16, 8, 9), dim3(256), 0, stream,
                     flow, wsf + 4);

  const size_t need_fused = (64 + 11 * (size_t)V3) * sizeof(float);
  if (ws_size >= need_fused) {
    // fused path: FJ holds 3 t-triples (9 planes) concurrently
    hipLaunchKernelGGL((n1_kernel<true>), dim3(8, 64, 1), dim3(256), 0, stream,
                       image, pred_image + (size_t)V3, FI, FJ);
    hipLaunchKernelGGL((n1_kernel<false>), dim3(8, 64, 2), dim3(256), 0, stream,
                       image, pred_image + 2 * (size_t)V3, FI,
                       FJ + 3 * (size_t)V3);
    hipLaunchKernelGGL(n2_kernel, dim3(16, 32, 3), dim3(256), 0, stream,
                       FI, FJ, wsf + 7);
  } else {
    // sequential path: one J triple reused across t (5 planes total)
    for (int t = 0; t < 3; ++t) {
      const float* J = pred_image + (size_t)(t + 1) * V3;
      if (t == 0) {
        hipLaunchKernelGGL((n1_kernel<true>), dim3(8, 64, 1), dim3(256), 0,
                           stream, image, J, FI, FJ);
      } else {
        hipLaunchKernelGGL((n1_kernel<false>), dim3(8, 64, 1), dim3(256), 0,
                           stream, image, J, FI, FJ);
      }
      hipLaunchKernelGGL(n2_kernel, dim3(16, 32, 1), dim3(256), 0, stream,
                         FI, FJ, wsf + 7);
    }
  }

  hipLaunchKernelGGL(final_kernel, dim3(1), dim3(1), 0, stream,
                     wsf, time_diff, out);
}

// Round 6
// 132.494 us; speedup vs baseline: 1.1912x; 1.1613x over previous
//
#include <hip/hip_runtime.h>

#define V3 (128 * 128 * 128)   // 2097152 voxels per volume

typedef _Float16 h8 __attribute__((ext_vector_type(8)));
typedef float    f8 __attribute__((ext_vector_type(8)));

// ---------------- block reduction (wave64) ----------------
__device__ __forceinline__ float block_reduce(float v, float* sm) {
#pragma unroll
  for (int off = 32; off > 0; off >>= 1) v += __shfl_down(v, off, 64);
  int lane = threadIdx.x & 63;
  int wid  = threadIdx.x >> 6;
  if (lane == 0) sm[wid] = v;
  __syncthreads();
  float r = 0.f;
  if ((int)threadIdx.x < (int)(blockDim.x >> 6)) r = sm[threadIdx.x];
  if (wid == 0) {
#pragma unroll
    for (int off = 4; off > 0; off >>= 1) r += __shfl_down(r, off, 64);
  }
  __syncthreads();
  return r;  // valid on thread 0
}

// masked fp16x8 load -> f32x8
__device__ __forceinline__ f8 ldh(const _Float16* __restrict__ p, size_t off,
                                  float m) {
  h8 q = *(const h8*)(p + off);
  f8 r = __builtin_convertvector(q, f8);
  return r * m;
}

// ---------------- pred_mask area sums (per t), float4 ----------------
__global__ __launch_bounds__(256) void area_kernel(const float* __restrict__ pm,
                                                   float* __restrict__ acc) {
  __shared__ float sm[8];
  const int t = blockIdx.y;
  const float* p = pm + (size_t)t * V3;
  const int n4 = V3 / 4;
  float s = 0.f;
  for (int i = blockIdx.x * blockDim.x + threadIdx.x; i < n4;
       i += gridDim.x * blockDim.x) {
    float4 a = *(const float4*)(p + 4 * (size_t)i);
    s += (a.x + a.y) + (a.z + a.w);
  }
  s = block_reduce(s, sm);
  if (threadIdx.x == 0) atomicAdd(acc + t, s);
}

// ---------------- flow gradient: register d-walk, 2 loads/iter ----------------
__global__ __launch_bounds__(256) void grad_kernel(const float* __restrict__ fl,
                                                   float* __restrict__ acc) {
  __shared__ float sm[8];
  const int w4 = threadIdx.x & 31;
  const int hl = threadIdx.x >> 5;
  const int h  = blockIdx.x * 8 + hl;
  const int d0 = blockIdx.y * 16;
  const int c  = blockIdx.z;
  const float* p = fl + (size_t)c * V3 + (size_t)h * 128 + w4 * 4;
  const bool hv = (h < 127);

  float s = 0.f;
  float4 cur  = *(const float4*)(p + (size_t)d0 * 16384);
  float4 curh = hv ? *(const float4*)(p + (size_t)d0 * 16384 + 128) : cur;

#pragma unroll
  for (int dd = 0; dd < 16; ++dd) {
    const int d = d0 + dd;
    const bool dv = (d < 127);
    float4 nxt = cur, nxth = curh;
    if (dv) {
      nxt = *(const float4*)(p + (size_t)(d + 1) * 16384);
      if (hv) nxth = *(const float4*)(p + (size_t)(d + 1) * 16384 + 128);
    }
    float x;
    x = cur.y - cur.x; s += x * x;
    x = cur.z - cur.y; s += x * x;
    x = cur.w - cur.z; s += x * x;
    float nx = __shfl_down(cur.x, 1, 64);
    if (w4 != 31) { x = nx - cur.w; s += x * x; }
    if (hv) {
      x = curh.x - cur.x; s += x * x;
      x = curh.y - cur.y; s += x * x;
      x = curh.z - cur.z; s += x * x;
      x = curh.w - cur.w; s += x * x;
    }
    if (dv) {
      x = nxt.x - cur.x; s += x * x;
      x = nxt.y - cur.y; s += x * x;
      x = nxt.z - cur.z; s += x * x;
      x = nxt.w - cur.w; s += x * x;
    }
    cur = nxt; curh = nxth;
  }
  s = block_reduce(s, sm);
  if (threadIdx.x == 0) atomicAdd(acc, s);
}

// ---------------- NCC pass 1: W-window + H-window box sums -> fp16 planes ----
// Block = 256 = 2 d-slices x 128 w. Grid = (8 h-chunks of 16, 64 d-pairs, NT).
template <bool WITH_I>
__global__ __launch_bounds__(256) void n1_kernel(const float* __restrict__ I0,
                                                 const float* __restrict__ Jall,
                                                 _Float16* __restrict__ FI,
                                                 _Float16* __restrict__ FJall) {
  constexpr int NF = WITH_I ? 5 : 3;
  __shared__ float sI[2][2][136];
  __shared__ float sJ[2][2][136];
  __shared__ float ring[2][9][NF][128];

  const int tz = blockIdx.z;
  const float* J = Jall + (size_t)tz * V3;
  _Float16* FJ = FJall + (size_t)tz * 3 * (size_t)V3;

  const int w  = threadIdx.x & 127;
  const int dl = threadIdx.x >> 7;
  const int d  = blockIdx.y * 2 + dl;
  const int h0 = blockIdx.x * 16;
  const float* Ib = I0 + (size_t)d * 16384;
  const float* Jb = J  + (size_t)d * 16384;

  if (w < 4) {
    sI[dl][0][w] = 0.f; sI[dl][1][w] = 0.f;
    sJ[dl][0][w] = 0.f; sJ[dl][1][w] = 0.f;
  }
  if (w >= 124) {
    sI[dl][0][w + 8] = 0.f; sI[dl][1][w + 8] = 0.f;
    sJ[dl][0][w + 8] = 0.f; sJ[dl][1][w + 8] = 0.f;
  }
#pragma unroll
  for (int sl = 0; sl < 9; ++sl)
#pragma unroll
    for (int f = 0; f < NF; ++f) ring[dl][sl][f][w] = 0.f;

  auto stage = [&](int hh) {
    if (hh >= 0 && hh < 128) {
      const int b = hh & 1;
      if (w < 32) {
        float4 v = *(const float4*)(Ib + hh * 128 + w * 4);
        *(float4*)&sI[dl][b][4 + w * 4] = v;
      } else if (w < 64) {
        const int l = w - 32;
        float4 v = *(const float4*)(Jb + hh * 128 + l * 4);
        *(float4*)&sJ[dl][b][4 + l * 4] = v;
      }
    }
  };

  float S[NF];
#pragma unroll
  for (int f = 0; f < NF; ++f) S[f] = 0.f;

  stage(h0 - 4);
  int slot = (h0 + 32) % 9;

  for (int hh = h0 - 4; hh < h0 + 20; ++hh) {
    __syncthreads();
    stage(hh + 1);
    const int b = hh & 1;
    const bool valid = (hh >= 0) && (hh < 128);

    float Wn[NF];
#pragma unroll
    for (int f = 0; f < NF; ++f) Wn[f] = 0.f;
    if (valid) {
#pragma unroll
      for (int k = 0; k < 9; ++k) {
        float a = sI[dl][b][w + k];
        float bb = sJ[dl][b][w + k];
        if (WITH_I) {
          Wn[0] += a; Wn[1] += a * a;
          Wn[2] += bb; Wn[3] += bb * bb; Wn[4] += a * bb;
        } else {
          Wn[0] += bb; Wn[1] += bb * bb; Wn[2] += a * bb;
        }
      }
    }

#pragma unroll
    for (int f = 0; f < NF; ++f) {
      float old = ring[dl][slot][f][w];
      ring[dl][slot][f][w] = Wn[f];
      S[f] += Wn[f] - old;
    }
    ++slot; if (slot == 9) slot = 0;

    const int ho = hh - 4;
    if (ho >= h0) {
      size_t base = (size_t)d * 16384 + (size_t)ho * 128 + w;
      if (WITH_I) {
        FI[base]                  = (_Float16)S[0];
        FI[(size_t)V3 + base]     = (_Float16)S[1];
        FJ[base]                  = (_Float16)S[2];
        FJ[(size_t)V3 + base]     = (_Float16)S[3];
        FJ[2 * (size_t)V3 + base] = (_Float16)S[4];
      } else {
        FJ[base]                  = (_Float16)S[0];
        FJ[(size_t)V3 + base]     = (_Float16)S[1];
        FJ[2 * (size_t)V3 + base] = (_Float16)S[2];
      }
    }
  }
}

// ---------------- NCC pass 2: fp16x8 running D-window + cc + reduce ----------
// Block = 128 = 8 h-rows x 16 w8-groups. Grid = (16 h-tiles, 16 d-chunks, NT).
__global__ __launch_bounds__(128) void n2_kernel(const _Float16* __restrict__ FI,
                                                 const _Float16* __restrict__ FJall,
                                                 float* __restrict__ acc) {
  __shared__ float sm[8];
  const _Float16* FJ = FJall + (size_t)blockIdx.z * 3 * (size_t)V3;
  const int w8 = threadIdx.x & 15;
  const int h  = blockIdx.x * 8 + (threadIdx.x >> 4);
  const int d0 = blockIdx.y * 8;
  const size_t hw = (size_t)h * 128 + w8 * 8;

  const _Float16* P0 = FI;
  const _Float16* P1 = FI + (size_t)V3;
  const _Float16* P2 = FJ;
  const _Float16* P3 = FJ + (size_t)V3;
  const _Float16* P4 = FJ + 2 * (size_t)V3;

  f8 S0 = {}, S1 = {}, S2 = {}, S3 = {}, S4 = {};
#pragma unroll
  for (int k = 0; k < 9; ++k) {
    const int dd = d0 - 4 + k;     // <= 124, only low clamp matters
    const float m = (dd >= 0) ? 1.f : 0.f;
    const size_t a = (size_t)(dd >= 0 ? dd : 0) * 16384 + hw;
    S0 += ldh(P0, a, m);
    S1 += ldh(P1, a, m);
    S2 += ldh(P2, a, m);
    S3 += ldh(P3, a, m);
    S4 += ldh(P4, a, m);
  }

  const float inv_win = 1.0f / 729.0f;
  float accv = 0.f;
#pragma unroll
  for (int dd = 0; dd < 8; ++dd) {
    const int d = d0 + dd;
    f8 cross = S4 - S0 * S2 * inv_win;
    f8 iv    = S1 - S0 * S0 * inv_win;
    f8 jv    = S3 - S2 * S2 * inv_win;
    f8 den   = iv * jv + 1e-5f;
#pragma unroll
    for (int i = 0; i < 8; ++i)
      accv += cross[i] * cross[i] * __builtin_amdgcn_rcpf(den[i]);

    const int da = d + 5, ds = d - 4;
    const float ma = (da < 128) ? 1.f : 0.f;
    const float ms = (ds >= 0) ? 1.f : 0.f;
    const size_t aa = (size_t)(da < 128 ? da : 0) * 16384 + hw;
    const size_t as = (size_t)(ds >= 0 ? ds : 0) * 16384 + hw;
    S0 += ldh(P0, aa, ma) - ldh(P0, as, ms);
    S1 += ldh(P1, aa, ma) - ldh(P1, as, ms);
    S2 += ldh(P2, aa, ma) - ldh(P2, as, ms);
    S3 += ldh(P3, aa, ma) - ldh(P3, as, ms);
    S4 += ldh(P4, aa, ma) - ldh(P4, as, ms);
  }

  accv = block_reduce(accv, sm);
  if (threadIdx.x == 0) atomicAdd(acc, accv);
}

// ---------------- final scalar combine ----------------
__global__ void final_kernel(const float* __restrict__ ws,
                             const float* __restrict__ td,
                             float* __restrict__ out) {
  if (threadIdx.x != 0 || blockIdx.x != 0) return;
  float area[4];
  float amax = -1e30f;
#pragma unroll
  for (int t = 0; t < 4; ++t) {
    area[t] = ws[t];
    amax = fmaxf(amax, area[t]);
  }
  float a[4];
#pragma unroll
  for (int t = 0; t < 4; ++t) a[t] = area[t] / amax;

  float sc = 0.f;
  int cnt = 0;
  for (int i = 0; i < 2; ++i)
    for (int j = i + 1; j < 3; ++j)
      for (int k = j + 1; k < 4; ++k) {
        float lam = (td[j] - td[i] + 1e-5f) / (td[k] - td[i] + 1e-5f);
        float e = a[j] - a[i] - lam * (a[k] - a[i]);
        sc += e * e;
        ++cnt;
      }
  sc /= (float)cnt;

  float ncc  = 1.0f - ws[7] / (3.0f * (float)V3);
  float grad = ws[4] / (3.0f * 9.0f * 127.0f * 128.0f * 128.0f);
  out[0] = ncc + 0.1f * grad + 0.1f * sc;
}

extern "C" void kernel_launch(void* const* d_in, const int* in_sizes, int n_in,
                              void* d_out, int out_size, void* d_ws, size_t ws_size,
                              hipStream_t stream) {
  const float* image      = (const float*)d_in[0];
  // d_in[1] = mask (unused by the reference loss)
  const float* pred_image = (const float*)d_in[2];
  const float* pred_mask  = (const float*)d_in[3];
  const float* flow       = (const float*)d_in[4];
  const float* time_diff  = (const float*)d_in[5];
  float* out = (float*)d_out;
  float* wsf = (float*)d_ws;
  _Float16* FI = (_Float16*)(wsf + 64);   // 2 fp16 planes (I_sum, I2_sum)
  _Float16* FJ = FI + 2 * (size_t)V3;     // fp16 J plane-triples

  // zero scalar accumulators: [0..3] area, [4] grad sum, [7] cc sum
  hipMemsetAsync(d_ws, 0, 256, stream);

  hipLaunchKernelGGL(area_kernel, dim3(512, 4), dim3(256), 0, stream,
                     pred_mask, wsf);
  hipLaunchKernelGGL(grad_kernel, dim3(16, 8, 9), dim3(256), 0, stream,
                     flow, wsf + 4);

  const size_t need_fused = 256 + 11 * (size_t)V3 * sizeof(_Float16);
  if (ws_size >= need_fused) {
    // fused path: FJ holds 3 t-triples (9 fp16 planes) concurrently
    hipLaunchKernelGGL((n1_kernel<true>), dim3(8, 64, 1), dim3(256), 0, stream,
                       image, pred_image + (size_t)V3, FI, FJ);
    hipLaunchKernelGGL((n1_kernel<false>), dim3(8, 64, 2), dim3(256), 0, stream,
                       image, pred_image + 2 * (size_t)V3, FI,
                       FJ + 3 * (size_t)V3);
    hipLaunchKernelGGL(n2_kernel, dim3(16, 16, 3), dim3(128), 0, stream,
                       FI, FJ, wsf + 7);
  } else {
    // sequential path: one J triple reused across t
    for (int t = 0; t < 3; ++t) {
      const float* J = pred_image + (size_t)(t + 1) * V3;
      if (t == 0) {
        hipLaunchKernelGGL((n1_kernel<true>), dim3(8, 64, 1), dim3(256), 0,
                           stream, image, J, FI, FJ);
      } else {
        hipLaunchKernelGGL((n1_kernel<false>), dim3(8, 64, 1), dim3(256), 0,
                           stream, image, J, FI, FJ);
      }
      hipLaunchKernelGGL(n2_kernel, dim3(16, 16, 1), dim3(128), 0, stream,
                         FI, FJ, wsf + 7);
    }
  }

  hipLaunchKernelGGL(final_kernel, dim3(1), dim3(1), 0, stream,
                     wsf, time_diff, out);
}